// Round 1
// baseline (508.113 us; speedup 1.0000x reference)
//
#include <hip/hip_runtime.h>

#define NB 32
#define NA 5
#define NC 80
#define NH 64
#define NW 64
#define MAXT 50
#define CH 85
#define HW (NH*NW)
#define NCELL (NB*NA*HW)

// workspace layout (in floats)
#define TGT_BASE 16
#define TGT_STRIDE 336
#define ENT_BASE (TGT_BASE + NB*TGT_STRIDE)
#define ENT_STRIDE (8 + 8*MAXT)
// within a per-batch target block: [0](int)=nvalid, then 5 arrays (stride 64):
#define T_XLO 16
#define T_XHI 80
#define T_YLO 144
#define T_YHI 208
#define T_GA  272   // stores 0.375 * gw * gh

__constant__ float c_aw[NA] = {42.3f/32.0f, 102.2f/32.0f, 161.8f/32.0f, 303.1f/32.0f, 359.6f/32.0f};
__constant__ float c_ah[NA] = {55.4f/32.0f, 128.3f/32.0f, 259.2f/32.0f, 154.9f/32.0f, 320.2f/32.0f};

__device__ __forceinline__ float sigm(float x) {
    return __builtin_amdgcn_rcpf(1.0f + __expf(-x));
}

// Per-batch target preprocessing + last-wins dedup of the scatter.
__global__ void prep_kernel(const float* __restrict__ out, const float* __restrict__ tgt,
                            float* __restrict__ W) {
    const int b = blockIdx.x;
    const int t = threadIdx.x;
    if (b == 0 && t == 0) W[0] = 0.0f;   // zero loss accumulator (ws is poisoned each call)

    __shared__ int   s_id[MAXT];
    __shared__ float s_tx[MAXT], s_ty[MAXT], s_tw[MAXT], s_th[MAXT], s_ti[MAXT];
    __shared__ int   s_cl[MAXT];

    bool iszero = true;
    float gcls = 0.f, gx = 0.f, gy = 0.f, gw = 0.f, gh = 0.f;
    if (t < MAXT) {
        const float* p = tgt + (b*MAXT + t)*5;
        gcls = p[0];
        float rx = p[1];
        iszero = (rx == 0.0f);
        gx = rx * (float)NW;
        gy = p[2] * (float)NH;
        gw = p[3] * (float)NW;
        gh = p[4] * (float)NH;
    }
    // valid = cumprod(x != 0): first-zero cutoff. Lanes >= MAXT report zero -> nvalid <= MAXT.
    unsigned long long mz = __ballot(iszero);
    const int nvalid = __ffsll(mz) - 1;

    float* TB = W + TGT_BASE + (size_t)b*TGT_STRIDE;
    if (t < MAXT) {
        TB[T_XLO + t] = gx - 0.5f*gw;
        TB[T_XHI + t] = gx + 0.5f*gw;
        TB[T_YLO + t] = gy - 0.5f*gh;
        TB[T_YHI + t] = gy + 0.5f*gh;
        TB[T_GA  + t] = 0.375f * gw * gh;

        // best anchor (first-max wins, like argmax)
        float garea = gw * gh;
        float best = -1.0f; int bn = 0;
        #pragma unroll
        for (int n = 0; n < NA; n++) {
            float inter = fminf(gw, c_aw[n]) * fminf(gh, c_ah[n]);
            float uni = garea + c_aw[n]*c_ah[n] - inter;
            float r = inter / uni;
            if (r > best) { best = r; bn = n; }
        }
        int gi = (int)gx; gi = gi < 0 ? 0 : (gi > NW-1 ? NW-1 : gi);
        int gj = (int)gy; gj = gj < 0 ? 0 : (gj > NH-1 ? NH-1 : gj);
        float awb = c_aw[bn], ahb = c_ah[bn];

        // gather prediction at (b, bn, gj, gi) for t_iou
        int base = ((b*NA + bn)*CH)*HW + gj*NW + gi;
        float ox = out[base];
        float oy = out[base + HW];
        float ow = out[base + 2*HW];
        float oh = out[base + 3*HW];
        float px = sigm(ox) + (float)gi;
        float py = sigm(oy) + (float)gj;
        float pw = __expf(ow) * awb;
        float ph = __expf(oh) * ahb;
        float iw = fminf(gx + 0.5f*gw, px + 0.5f*pw) - fmaxf(gx - 0.5f*gw, px - 0.5f*pw);
        float ih = fminf(gy + 0.5f*gh, py + 0.5f*ph) - fmaxf(gy - 0.5f*gh, py - 0.5f*ph);
        float inter = fmaxf(iw, 0.f) * fmaxf(ih, 0.f);
        float tiou = inter / (garea + pw*ph - inter);

        s_id[t] = (bn*NH + gj)*NW + gi;
        s_tx[t] = gx - (float)gi;
        s_ty[t] = gy - (float)gj;
        s_tw[t] = __logf(gw / awb);
        s_th[t] = __logf(gh / ahb);
        s_ti[t] = tiou;
        s_cl[t] = (int)gcls;
    }
    __syncthreads();
    if (t == 0) {
        ((int*)TB)[0] = nvalid;
        float* EB = W + ENT_BASE + (size_t)b*ENT_STRIDE;
        int keep[MAXT]; int cnt = 0;
        for (int u = 0; u < nvalid; u++) {        // sequential scatter: last write wins
            int id = s_id[u]; int f = -1;
            for (int k = 0; k < cnt; k++) if (s_id[keep[k]] == id) { f = k; break; }
            if (f >= 0) keep[f] = u; else keep[cnt++] = u;
        }
        ((int*)EB)[0] = cnt;
        for (int k = 0; k < cnt; k++) {
            int u = keep[k];
            float* e = EB + 8 + k*8;
            ((int*)e)[0] = s_id[u];
            e[1] = s_tx[u]; e[2] = s_ty[u]; e[3] = s_tw[u]; e[4] = s_th[u]; e[5] = s_ti[u];
            ((int*)e)[6] = s_cl[u];
        }
    }
}

// Base loss over all cells. conf_mask0 test without division:
// inter/union > 0.6  <=>  inter > 0.375*(pa+ga)  <=>  max_t(inter_t - 0.375*ga_t) > 0.375*pa
__global__ __launch_bounds__(256) void main_kernel(const float* __restrict__ out,
                                                   float* __restrict__ W) {
    const int cell = blockIdx.x * 256 + threadIdx.x;
    const int b = cell / (NA*HW);          // uniform per block (256 | HW)
    const int rem = cell - b*(NA*HW);
    const int a = rem / HW;                // uniform per block
    const int ji = rem & (HW-1);
    const int i = ji & (NW-1);
    const int j = ji >> 6;

    __shared__ float sxl[MAXT], sxh[MAXT], syl[MAXT], syh[MAXT], sga[MAXT];
    __shared__ int s_nv;
    const float* TB = W + TGT_BASE + (size_t)b*TGT_STRIDE;
    if (threadIdx.x == 0) s_nv = ((const int*)TB)[0];
    if (threadIdx.x < MAXT) {
        int t = threadIdx.x;
        sxl[t] = TB[T_XLO+t]; sxh[t] = TB[T_XHI+t];
        syl[t] = TB[T_YLO+t]; syh[t] = TB[T_YHI+t];
        sga[t] = TB[T_GA+t];
    }
    __syncthreads();

    const size_t base = (size_t)((b*NA + a)*CH)*HW + ji;
    const float ox = out[base];
    const float oy = out[base + HW];
    const float ow = out[base + 2*HW];
    const float oh = out[base + 3*HW];
    const float oc = out[base + 4*HW];

    const float sx = sigm(ox);
    const float sy = sigm(oy);
    const float sc = sigm(oc);
    const float pw = __expf(ow) * c_aw[a];
    const float ph = __expf(oh) * c_ah[a];
    const float px = sx + (float)i;
    const float py = sy + (float)j;
    const float pxl = px - 0.5f*pw, pxh = px + 0.5f*pw;
    const float pyl = py - 0.5f*ph, pyh = py + 0.5f*ph;
    const float pa375 = 0.375f * pw * ph;

    const int nv = s_nv;
    float m = -1.0f;
    for (int tt = 0; tt < nv; tt++) {
        float iw = fminf(pxh, sxh[tt]) - fmaxf(pxl, sxl[tt]);
        float ih = fminf(pyh, syh[tt]) - fmaxf(pyl, syl[tt]);
        float inter = fmaxf(iw, 0.f) * fmaxf(ih, 0.f);
        m = fmaxf(m, inter - sga[tt]);
    }
    const bool over = m > pa375;

    const float dx = sx - 0.5f, dy = sy - 0.5f;
    float v = dx*dx + dy*dy + ow*ow + oh*oh;
    if (!over) v += sc*sc;
    v *= 0.5f;

    for (int off = 32; off > 0; off >>= 1) v += __shfl_down(v, off);
    __shared__ float red[4];
    if ((threadIdx.x & 63) == 0) red[threadIdx.x >> 6] = v;
    __syncthreads();
    if (threadIdx.x == 0) atomicAdd(W, red[0]+red[1]+red[2]+red[3]);
}

// Correction at deduped scattered cells: replaces base coord/conf terms, adds cls term.
__global__ void corr_kernel(const float* __restrict__ out, float* __restrict__ W) {
    const int b = blockIdx.x;
    const int t = threadIdx.x;
    __shared__ float sxl[MAXT], sxh[MAXT], syl[MAXT], syh[MAXT], sga[MAXT];
    const float* TB = W + TGT_BASE + (size_t)b*TGT_STRIDE;
    const int nv = ((const int*)TB)[0];
    if (t < MAXT) {
        sxl[t] = TB[T_XLO+t]; sxh[t] = TB[T_XHI+t];
        syl[t] = TB[T_YLO+t]; syh[t] = TB[T_YHI+t];
        sga[t] = TB[T_GA+t];
    }
    __syncthreads();
    const float* EB = W + ENT_BASE + (size_t)b*ENT_STRIDE;
    const int cnt = ((const int*)EB)[0];
    float acc = 0.f;
    for (int e = t; e < cnt; e += 64) {
        const float* en = EB + 8 + e*8;
        const int id = ((const int*)en)[0];
        const float tx = en[1], ty = en[2], tw = en[3], th = en[4], ti = en[5];
        const int cls = ((const int*)en)[6];
        const int a = id >> 12;
        const int ji = id & (HW-1);
        const int i = ji & (NW-1);
        const int j = ji >> 6;
        const size_t base = (size_t)((b*NA + a)*CH)*HW + ji;
        const float ox = out[base];
        const float oy = out[base + HW];
        const float ow = out[base + 2*HW];
        const float oh = out[base + 3*HW];
        const float oc = out[base + 4*HW];
        const float sx = sigm(ox), sy = sigm(oy), sc = sigm(oc);

        const float dxn = sx - tx, dxo = sx - 0.5f;
        const float dyn = sy - ty, dyo = sy - 0.5f;
        const float dwn = ow - tw, dhn = oh - th;
        float d = dxn*dxn - dxo*dxo + dyn*dyn - dyo*dyo + dwn*dwn - ow*ow + dhn*dhn - oh*oh;

        // recompute conf_mask0 at this cell to subtract the base conf term
        const float pw = __expf(ow) * c_aw[a];
        const float ph = __expf(oh) * c_ah[a];
        const float px = sx + (float)i, py = sy + (float)j;
        const float pxl = px - 0.5f*pw, pxh = px + 0.5f*pw;
        const float pyl = py - 0.5f*ph, pyh = py + 0.5f*ph;
        const float pa375 = 0.375f * pw * ph;
        float mm = -1.0f;
        for (int u = 0; u < nv; u++) {
            float iw = fminf(pxh, sxh[u]) - fmaxf(pxl, sxl[u]);
            float ih = fminf(pyh, syh[u]) - fmaxf(pyl, syl[u]);
            float inter = fmaxf(iw, 0.f) * fmaxf(ih, 0.f);
            mm = fmaxf(mm, inter - sga[u]);
        }
        float dc = 5.f*(sc - ti)*(sc - ti);
        if (!(mm > pa375)) dc -= sc*sc;   // base had conf_mask0 * conf^2
        d += dc;
        acc += 0.5f * d;

        // class term: (logsumexp - picked) * 1
        const float* lg = out + base + 5*HW;
        float mx = lg[0];
        for (int c = 1; c < NC; c++) mx = fmaxf(mx, lg[(size_t)c*HW]);
        float s = 0.f;
        for (int c = 0; c < NC; c++) s += __expf(lg[(size_t)c*HW] - mx);
        acc += mx + __logf(s) - lg[(size_t)cls*HW];
    }
    for (int off = 32; off > 0; off >>= 1) acc += __shfl_down(acc, off);
    if (t == 0) atomicAdd(W, acc);
}

__global__ void fin_kernel(const float* __restrict__ W, float* __restrict__ res) {
    res[0] = W[0];
}

extern "C" void kernel_launch(void* const* d_in, const int* in_sizes, int n_in,
                              void* d_out, int out_size, void* d_ws, size_t ws_size,
                              hipStream_t stream) {
    const float* out = (const float*)d_in[0];
    const float* tgt = (const float*)d_in[1];
    float* W = (float*)d_ws;
    float* res = (float*)d_out;
    hipLaunchKernelGGL(prep_kernel, dim3(NB), dim3(64), 0, stream, out, tgt, W);
    hipLaunchKernelGGL(main_kernel, dim3(NCELL/256), dim3(256), 0, stream, out, W);
    hipLaunchKernelGGL(corr_kernel, dim3(NB), dim3(64), 0, stream, out, W);
    hipLaunchKernelGGL(fin_kernel, dim3(1), dim3(1), 0, stream, W, res);
}

// Round 2
// 329.803 us; speedup vs baseline: 1.5407x; 1.5407x over previous
//
#include <hip/hip_runtime.h>

#define NB 32
#define NA 5
#define NC 80
#define NH 64
#define NW 64
#define MAXT 50
#define CH 85
#define HW (NH*NW)
#define NCELL (NB*NA*HW)

// workspace layout (in floats)
#define TGT_BASE 16
#define TGT_STRIDE 336
#define ENT_BASE (TGT_BASE + NB*TGT_STRIDE)
#define ENT_STRIDE (8 + 8*MAXT)
// within a per-batch target block: [0](int)=nvalid, then 5 arrays (stride 64):
#define T_XLO 16
#define T_XHI 80
#define T_YLO 144
#define T_YHI 208
#define T_GA  272   // stores 0.375 * gw * gh

__constant__ float c_aw[NA] = {42.3f/32.0f, 102.2f/32.0f, 161.8f/32.0f, 303.1f/32.0f, 359.6f/32.0f};
__constant__ float c_ah[NA] = {55.4f/32.0f, 128.3f/32.0f, 259.2f/32.0f, 154.9f/32.0f, 320.2f/32.0f};

__device__ __forceinline__ float sigm(float x) {
    return __builtin_amdgcn_rcpf(1.0f + __expf(-x));
}

// Per-batch target preprocessing + last-wins dedup of the scatter.
// Dedup is parallel: lane t keeps its entry iff no later entry t'>t maps to the
// same cell id (matches sequential .at[].set last-write-wins). Dead entries get
// id=-1 and are skipped by corr_kernel. NO dynamically-indexed local arrays
// (previous version's thread-0 serial loop hit scratch memory: 188 us).
__global__ void prep_kernel(const float* __restrict__ out, const float* __restrict__ tgt,
                            float* __restrict__ W) {
    const int b = blockIdx.x;
    const int t = threadIdx.x;
    if (b == 0 && t == 0) W[0] = 0.0f;   // zero loss accumulator (ws is poisoned each call)

    __shared__ int s_id[MAXT];

    bool iszero = true;
    float gcls = 0.f, gx = 0.f, gy = 0.f, gw = 0.f, gh = 0.f;
    if (t < MAXT) {
        const float* p = tgt + (b*MAXT + t)*5;
        gcls = p[0];
        float rx = p[1];
        iszero = (rx == 0.0f);
        gx = rx * (float)NW;
        gy = p[2] * (float)NH;
        gw = p[3] * (float)NW;
        gh = p[4] * (float)NH;
    }
    // valid = cumprod(x != 0): first-zero cutoff. Lanes >= MAXT report zero -> nvalid <= MAXT.
    unsigned long long mz = __ballot(iszero);
    const int nvalid = __ffsll(mz) - 1;

    float* TB = W + TGT_BASE + (size_t)b*TGT_STRIDE;

    int   myid = -1;
    float tx = 0.f, ty = 0.f, tw = 0.f, th = 0.f, tiou = 0.f;
    int   mycl = 0;

    if (t < MAXT) {
        TB[T_XLO + t] = gx - 0.5f*gw;
        TB[T_XHI + t] = gx + 0.5f*gw;
        TB[T_YLO + t] = gy - 0.5f*gh;
        TB[T_YHI + t] = gy + 0.5f*gh;
        TB[T_GA  + t] = 0.375f * gw * gh;

        // best anchor (first-max wins, like argmax)
        float garea = gw * gh;
        float best = -1.0f; int bn = 0;
        #pragma unroll
        for (int n = 0; n < NA; n++) {
            float inter = fminf(gw, c_aw[n]) * fminf(gh, c_ah[n]);
            float uni = garea + c_aw[n]*c_ah[n] - inter;
            float r = inter / uni;
            if (r > best) { best = r; bn = n; }
        }
        int gi = (int)gx; gi = gi < 0 ? 0 : (gi > NW-1 ? NW-1 : gi);
        int gj = (int)gy; gj = gj < 0 ? 0 : (gj > NH-1 ? NH-1 : gj);
        float awb = c_aw[bn], ahb = c_ah[bn];

        // gather prediction at (b, bn, gj, gi) for t_iou
        int base = ((b*NA + bn)*CH)*HW + gj*NW + gi;
        float ox = out[base];
        float oy = out[base + HW];
        float ow = out[base + 2*HW];
        float oh = out[base + 3*HW];
        float px = sigm(ox) + (float)gi;
        float py = sigm(oy) + (float)gj;
        float pw = __expf(ow) * awb;
        float ph = __expf(oh) * ahb;
        float iw = fminf(gx + 0.5f*gw, px + 0.5f*pw) - fmaxf(gx - 0.5f*gw, px - 0.5f*pw);
        float ih = fminf(gy + 0.5f*gh, py + 0.5f*ph) - fmaxf(gy - 0.5f*gh, py - 0.5f*ph);
        float inter = fmaxf(iw, 0.f) * fmaxf(ih, 0.f);
        tiou = inter / (garea + pw*ph - inter);

        myid = (bn*NH + gj)*NW + gi;
        tx = gx - (float)gi;
        ty = gy - (float)gj;
        tw = __logf(gw / awb);
        th = __logf(gh / ahb);
        mycl = (int)gcls;
        s_id[t] = myid;
    }
    __syncthreads();

    // parallel last-wins dedup: lane t is dead if any later valid lane has same id
    bool keepf = (t < nvalid);
    if (keepf) {
        for (int u = t + 1; u < nvalid; u++) {
            if (s_id[u] == myid) { keepf = false; break; }
        }
    }

    float* EB = W + ENT_BASE + (size_t)b*ENT_STRIDE;
    if (t == 0) {
        ((int*)TB)[0] = nvalid;
        ((int*)EB)[0] = nvalid;
    }
    if (t < nvalid) {
        float* e = EB + 8 + t*8;
        ((int*)e)[0] = keepf ? myid : -1;
        e[1] = tx; e[2] = ty; e[3] = tw; e[4] = th; e[5] = tiou;
        ((int*)e)[6] = mycl;
    }
}

// Base loss over all cells. conf_mask0 test without division:
// inter/union > 0.6  <=>  inter > 0.375*(pa+ga)  <=>  max_t(inter_t - 0.375*ga_t) > 0.375*pa
__global__ __launch_bounds__(256) void main_kernel(const float* __restrict__ out,
                                                   float* __restrict__ W) {
    const int cell = blockIdx.x * 256 + threadIdx.x;
    const int b = cell / (NA*HW);          // uniform per block (256 | HW)
    const int rem = cell - b*(NA*HW);
    const int a = rem / HW;                // uniform per block
    const int ji = rem & (HW-1);
    const int i = ji & (NW-1);
    const int j = ji >> 6;

    __shared__ float sxl[MAXT], sxh[MAXT], syl[MAXT], syh[MAXT], sga[MAXT];
    __shared__ int s_nv;
    const float* TB = W + TGT_BASE + (size_t)b*TGT_STRIDE;
    if (threadIdx.x == 0) s_nv = ((const int*)TB)[0];
    if (threadIdx.x < MAXT) {
        int t = threadIdx.x;
        sxl[t] = TB[T_XLO+t]; sxh[t] = TB[T_XHI+t];
        syl[t] = TB[T_YLO+t]; syh[t] = TB[T_YHI+t];
        sga[t] = TB[T_GA+t];
    }
    __syncthreads();

    const size_t base = (size_t)((b*NA + a)*CH)*HW + ji;
    const float ox = out[base];
    const float oy = out[base + HW];
    const float ow = out[base + 2*HW];
    const float oh = out[base + 3*HW];
    const float oc = out[base + 4*HW];

    const float sx = sigm(ox);
    const float sy = sigm(oy);
    const float sc = sigm(oc);
    const float pw = __expf(ow) * c_aw[a];
    const float ph = __expf(oh) * c_ah[a];
    const float px = sx + (float)i;
    const float py = sy + (float)j;
    const float pxl = px - 0.5f*pw, pxh = px + 0.5f*pw;
    const float pyl = py - 0.5f*ph, pyh = py + 0.5f*ph;
    const float pa375 = 0.375f * pw * ph;

    const int nv = s_nv;
    float m = -1.0f;
    for (int tt = 0; tt < nv; tt++) {
        float iw = fminf(pxh, sxh[tt]) - fmaxf(pxl, sxl[tt]);
        float ih = fminf(pyh, syh[tt]) - fmaxf(pyl, syl[tt]);
        float inter = fmaxf(iw, 0.f) * fmaxf(ih, 0.f);
        m = fmaxf(m, inter - sga[tt]);
    }
    const bool over = m > pa375;

    const float dx = sx - 0.5f, dy = sy - 0.5f;
    float v = dx*dx + dy*dy + ow*ow + oh*oh;
    if (!over) v += sc*sc;
    v *= 0.5f;

    for (int off = 32; off > 0; off >>= 1) v += __shfl_down(v, off);
    __shared__ float red[4];
    if ((threadIdx.x & 63) == 0) red[threadIdx.x >> 6] = v;
    __syncthreads();
    if (threadIdx.x == 0) atomicAdd(W, red[0]+red[1]+red[2]+red[3]);
}

// Correction at deduped scattered cells: replaces base coord/conf terms, adds cls term.
__global__ void corr_kernel(const float* __restrict__ out, float* __restrict__ W) {
    const int b = blockIdx.x;
    const int t = threadIdx.x;
    __shared__ float sxl[MAXT], sxh[MAXT], syl[MAXT], syh[MAXT], sga[MAXT];
    const float* TB = W + TGT_BASE + (size_t)b*TGT_STRIDE;
    const int nv = ((const int*)TB)[0];
    if (t < MAXT) {
        sxl[t] = TB[T_XLO+t]; sxh[t] = TB[T_XHI+t];
        syl[t] = TB[T_YLO+t]; syh[t] = TB[T_YHI+t];
        sga[t] = TB[T_GA+t];
    }
    __syncthreads();
    const float* EB = W + ENT_BASE + (size_t)b*ENT_STRIDE;
    const int cnt = ((const int*)EB)[0];
    float acc = 0.f;
    for (int e = t; e < cnt; e += 64) {
        const float* en = EB + 8 + e*8;
        const int id = ((const int*)en)[0];
        if (id < 0) continue;              // deduped-away entry (an earlier duplicate)
        const float tx = en[1], ty = en[2], tw = en[3], th = en[4], ti = en[5];
        const int cls = ((const int*)en)[6];
        const int a = id >> 12;
        const int ji = id & (HW-1);
        const int i = ji & (NW-1);
        const int j = ji >> 6;
        const size_t base = (size_t)((b*NA + a)*CH)*HW + ji;
        const float ox = out[base];
        const float oy = out[base + HW];
        const float ow = out[base + 2*HW];
        const float oh = out[base + 3*HW];
        const float oc = out[base + 4*HW];
        const float sx = sigm(ox), sy = sigm(oy), sc = sigm(oc);

        const float dxn = sx - tx, dxo = sx - 0.5f;
        const float dyn = sy - ty, dyo = sy - 0.5f;
        const float dwn = ow - tw, dhn = oh - th;
        float d = dxn*dxn - dxo*dxo + dyn*dyn - dyo*dyo + dwn*dwn - ow*ow + dhn*dhn - oh*oh;

        // recompute conf_mask0 at this cell to subtract the base conf term
        const float pw = __expf(ow) * c_aw[a];
        const float ph = __expf(oh) * c_ah[a];
        const float px = sx + (float)i, py = sy + (float)j;
        const float pxl = px - 0.5f*pw, pxh = px + 0.5f*pw;
        const float pyl = py - 0.5f*ph, pyh = py + 0.5f*ph;
        const float pa375 = 0.375f * pw * ph;
        float mm = -1.0f;
        for (int u = 0; u < nv; u++) {
            float iw = fminf(pxh, sxh[u]) - fmaxf(pxl, sxl[u]);
            float ih = fminf(pyh, syh[u]) - fmaxf(pyl, syl[u]);
            float inter = fmaxf(iw, 0.f) * fmaxf(ih, 0.f);
            mm = fmaxf(mm, inter - sga[u]);
        }
        float dc = 5.f*(sc - ti)*(sc - ti);
        if (!(mm > pa375)) dc -= sc*sc;   // base had conf_mask0 * conf^2
        d += dc;
        acc += 0.5f * d;

        // class term: (logsumexp - picked) * 1
        const float* lg = out + base + 5*HW;
        float mx = lg[0];
        for (int c = 1; c < NC; c++) mx = fmaxf(mx, lg[(size_t)c*HW]);
        float s = 0.f;
        for (int c = 0; c < NC; c++) s += __expf(lg[(size_t)c*HW] - mx);
        acc += mx + __logf(s) - lg[(size_t)cls*HW];
    }
    for (int off = 32; off > 0; off >>= 1) acc += __shfl_down(acc, off);
    if (t == 0) atomicAdd(W, acc);
}

__global__ void fin_kernel(const float* __restrict__ W, float* __restrict__ res) {
    res[0] = W[0];
}

extern "C" void kernel_launch(void* const* d_in, const int* in_sizes, int n_in,
                              void* d_out, int out_size, void* d_ws, size_t ws_size,
                              hipStream_t stream) {
    const float* out = (const float*)d_in[0];
    const float* tgt = (const float*)d_in[1];
    float* W = (float*)d_ws;
    float* res = (float*)d_out;
    hipLaunchKernelGGL(prep_kernel, dim3(NB), dim3(64), 0, stream, out, tgt, W);
    hipLaunchKernelGGL(main_kernel, dim3(NCELL/256), dim3(256), 0, stream, out, W);
    hipLaunchKernelGGL(corr_kernel, dim3(NB), dim3(64), 0, stream, out, W);
    hipLaunchKernelGGL(fin_kernel, dim3(1), dim3(1), 0, stream, W, res);
}